// Round 1
// baseline (446.074 us; speedup 1.0000x reference)
//
#include <hip/hip_runtime.h>

// TAACTD loss: reverse-time TD(λ=?) style recurrence over T=256, B=65536.
// out[t] = (ret_t - value[t])^2 for t in [0, T-2]; out[T-1] = 0.
// ret_t = acc_{t+1} * (discount[t+1]*GAMMA) + reward[t+1]
// acc_t = il_t * target_value[t] + (1-il_t) * ret_t
// il_t  = (step_type[t]==2) | ((t>0) & (rollout_b[t]|b[t]))

#define GAMMA_F 0.98f

constexpr int T = 256;
constexpr int B = 65536;

__global__ __launch_bounds__(256) void td_loss_kernel(
    const float* __restrict__ reward,
    const float* __restrict__ discount,
    const float* __restrict__ value,
    const float* __restrict__ target_value,
    const int*   __restrict__ b_arr,
    const int*   __restrict__ rollout_b,
    const int*   __restrict__ step_type,
    float*       __restrict__ out)
{
    const int col = blockIdx.x * blockDim.x + threadIdx.x;
    if (col >= B) return;

    // init: acc = target_value[T-1], last output row is zeros
    float acc = target_value[(size_t)(T - 1) * B + col];
    out[(size_t)(T - 1) * B + col] = 0.0f;

    // Reverse scan. All loads per iteration are independent of the serial
    // acc chain -> unroll for ILP / outstanding-load depth (latency hiding
    // at only 4 waves/CU of occupancy).
    #pragma unroll 4
    for (int t = T - 2; t >= 0; --t) {
        const size_t idx_t = (size_t)t * B + col;
        const size_t idx_n = idx_t + B;

        const float disc_n = discount[idx_n] * GAMMA_F;
        const float rew_n  = reward[idx_n];
        const float val_t  = target_value[idx_t];
        const float v_t    = value[idx_t];
        const int   st     = step_type[idx_t];
        const int   bbv    = (t > 0) ? (rollout_b[idx_t] | b_arr[idx_t]) : 0;

        const float il  = ((st == 2) || (bbv != 0)) ? 1.0f : 0.0f;
        const float ret = acc * disc_n + rew_n;
        acc = il * val_t + (1.0f - il) * ret;

        const float d = ret - v_t;
        out[idx_t] = d * d;
    }
}

extern "C" void kernel_launch(void* const* d_in, const int* in_sizes, int n_in,
                              void* d_out, int out_size, void* d_ws, size_t ws_size,
                              hipStream_t stream) {
    const float* reward       = (const float*)d_in[0];
    const float* discount     = (const float*)d_in[1];
    const float* value        = (const float*)d_in[2];
    const float* target_value = (const float*)d_in[3];
    const int*   b_arr        = (const int*)d_in[4];
    const int*   rollout_b    = (const int*)d_in[5];
    const int*   step_type    = (const int*)d_in[6];
    float*       out          = (float*)d_out;

    const int threads = 256;
    const int blocks  = B / threads; // 65536/256 = 256 blocks (1 per CU)
    td_loss_kernel<<<blocks, threads, 0, stream>>>(
        reward, discount, value, target_value, b_arr, rollout_b, step_type, out);
}

// Round 2
// 412.332 us; speedup vs baseline: 1.0818x; 1.0818x over previous
//
#include <hip/hip_runtime.h>

// TAACTD loss: reverse-time affine recurrence over T=256, B=65536.
// out[t] = (ret_t - value[t])^2 for t in [0, T-2]; out[T-1] = 0.
// ret_t = acc_{t+1} * (discount[t+1]*GAMMA) + reward[t+1]
// acc_t = il_t ? target_value[t] : ret_t
// il_t  = (step_type[t]==2) | ((t>0) & (rollout_b[t]|b[t]))
//
// Latency-bound fix (round 2): explicit software pipeline, rotating register
// buffers, prefetch depth D=8 -> 49 outstanding dword loads/lane (vmcnt<=63),
// ~57 KB in flight per CU at 4 waves/CU. No LDS, no barriers: each lane owns
// one column, so waits are counted per-register vmcnt, never a full drain.

#define GAMMA_F 0.98f

constexpr int T = 256;
constexpr int B = 65536;
constexpr int NSTEP = T - 1;  // 255 steps: t = 254 .. 0
constexpr int D = 8;          // prefetch depth; 7 loads/step * 8 = 56 <= 63 (vmcnt cap)

__global__ __launch_bounds__(256) void td_loss_kernel(
    const float* __restrict__ reward,
    const float* __restrict__ discount,
    const float* __restrict__ value,
    const float* __restrict__ target_value,
    const int*   __restrict__ b_arr,
    const int*   __restrict__ rollout_b,
    const int*   __restrict__ step_type,
    float*       __restrict__ out)
{
    const int col = blockIdx.x * 256 + threadIdx.x;

    // rotating prefetch buffers (slot j holds data for step s with s % D == j)
    float pd[D], pr[D], pv[D], pt[D];
    int   pb[D], prb[D], pst[D];

    float acc = target_value[(size_t)(T - 1) * B + col];
    out[(size_t)(T - 1) * B + col] = 0.0f;  // d_out is poisoned; row T-1 must be 0

    // prologue: fill all D slots (steps s = 0..D-1, i.e. t = 254..247)
    #pragma unroll
    for (int j = 0; j < D; ++j) {
        const int t = NSTEP - 1 - j;
        const size_t it = (size_t)t * B + col;
        pd[j]  = discount[it + B];
        pr[j]  = reward[it + B];
        pv[j]  = value[it];
        pt[j]  = target_value[it];
        pb[j]  = b_arr[it];
        prb[j] = rollout_b[it];
        pst[j] = step_type[it];
    }

    // main loop: 31 outer iterations x 8 steps = s = 0..247
    #pragma unroll 1
    for (int s0 = 0; s0 < NSTEP - (D - 1); s0 += D) {
        #pragma unroll
        for (int j = 0; j < D; ++j) {
            const int s = s0 + j;
            const int t = NSTEP - 1 - s;

            // ---- consume slot j (step s) ----
            const float disc_n = pd[j] * GAMMA_F;
            const float ret    = acc * disc_n + pr[j];
            const int   bbv    = pb[j] | prb[j];
            const bool  il     = (pst[j] == 2) || ((t > 0) && (bbv != 0));
            acc = il ? pt[j] : ret;
            const float dd = ret - pv[j];
            out[(size_t)t * B + col] = dd * dd;

            // ---- prefetch step s + D into slot j ----
            const int sp = s + D;
            if (sp < NSTEP) {
                const int tp = NSTEP - 1 - sp;
                const size_t it = (size_t)tp * B + col;
                pd[j]  = discount[it + B];
                pr[j]  = reward[it + B];
                pv[j]  = value[it];
                pt[j]  = target_value[it];
                pb[j]  = b_arr[it];
                prb[j] = rollout_b[it];
                pst[j] = step_type[it];
            }
        }
    }

    // tail: s = 248..254 (slots 0..6), no prefetch
    #pragma unroll
    for (int j = 0; j < D - 1; ++j) {
        const int s = (NSTEP - (D - 1)) + j;  // 248 + j
        const int t = NSTEP - 1 - s;          // 6 .. 0

        const float disc_n = pd[j] * GAMMA_F;
        const float ret    = acc * disc_n + pr[j];
        const int   bbv    = pb[j] | prb[j];
        const bool  il     = (pst[j] == 2) || ((t > 0) && (bbv != 0));
        acc = il ? pt[j] : ret;
        const float dd = ret - pv[j];
        out[(size_t)t * B + col] = dd * dd;
    }
}

extern "C" void kernel_launch(void* const* d_in, const int* in_sizes, int n_in,
                              void* d_out, int out_size, void* d_ws, size_t ws_size,
                              hipStream_t stream) {
    const float* reward       = (const float*)d_in[0];
    const float* discount     = (const float*)d_in[1];
    const float* value        = (const float*)d_in[2];
    const float* target_value = (const float*)d_in[3];
    const int*   b_arr        = (const int*)d_in[4];
    const int*   rollout_b    = (const int*)d_in[5];
    const int*   step_type    = (const int*)d_in[6];
    float*       out          = (float*)d_out;

    const int threads = 256;
    const int blocks  = B / threads;  // 256 blocks -> 1024 waves = 1/SIMD
    td_loss_kernel<<<blocks, threads, 0, stream>>>(
        reward, discount, value, target_value, b_arr, rollout_b, step_type, out);
}